// Round 4
// baseline (3041.270 us; speedup 1.0000x reference)
//
#include <hip/hip_runtime.h>
#include <hip/hip_bf16.h>
#include <stdint.h>

typedef __bf16 bf16;
typedef unsigned int uint;
typedef __attribute__((ext_vector_type(8))) __bf16 bf16x8;
typedef __attribute__((ext_vector_type(4))) float floatx4;

#define DEV static __device__ __forceinline__

typedef const __attribute__((address_space(1))) void* gptr_t;
typedef __attribute__((address_space(3))) void* lptr_t;

DEV void gload16(const void* g, void* l) {
  __builtin_amdgcn_global_load_lds((gptr_t)g, (lptr_t)l, 16, 0, 0);
}

DEV uint f2b2(float x, float y) {
  union { bf16 h[2]; uint u; } pk;
  pk.h[0] = (bf16)x; pk.h[1] = (bf16)y;
  return pk.u;
}

// ---------------------------------------------------------------------------
// GEMM: C[M][N] (op)= A[M][K] * Bt[N][K]^T (+ bias[n])
// 128x128 tile, BK=64, 256 threads, MFMA 16x16x32 bf16. XOR-8 swizzled LDS,
// XCD-aware block swizzle. Proven ~875 TF @ K=768 (structural ceiling for
// this K per R1 experiment: 256^2 8-phase regressed at NT=12).
// ---------------------------------------------------------------------------
#define EP_STORE_BF16 0
#define EP_STORE_F32  1
#define EP_ACCUM_F32  2
#define EP_RELU_BF16  3
#define EP_QKV        4
#define EP_FINAL      5   // read C(fp32), add; write prefix rows to out fp32

template<int MODE>
__global__ __launch_bounds__(256, 4)
void gemm_bt(const bf16* __restrict__ A, const bf16* __restrict__ Bt,
             void* __restrict__ Cv, void* __restrict__ Cv2,
             const float* __restrict__ bias, int K, int ldc)
{
  __shared__ bf16 As[128 * 64];
  __shared__ bf16 Bs[128 * 64];
  const int tid  = threadIdx.x;
  const int wave = tid >> 6;
  const int lane = tid & 63;

  // XCD-aware swizzle (identity when gridDim.y % 8 != 0)
  int bx = blockIdx.x, by = blockIdx.y;
  const int gx = (int)gridDim.x, gy = (int)gridDim.y;
  if ((gy & 7) == 0) {
    const int flat = by * gx + bx;
    const int xcd  = flat & 7;
    const int s    = flat >> 3;
    const int rows_per = gy >> 3;
    const int m_local  = s / gx;
    bx = s - m_local * gx;
    by = xcd * rows_per + m_local;
  }
  const int m0 = by * 128;
  const int n0 = bx * 128;
  const int wm = (wave >> 1) * 64;
  const int wn = (wave & 1) * 64;

  const int rA = tid >> 3;                 // local row 0..31 (call adds j*32)
  const int lc = (tid & 7) ^ (rA & 7);     // logical 16B-chunk (const: 32%8==0)
  const bf16* Asrc = A  + (size_t)(m0 + rA) * K + lc * 8;
  const bf16* Bsrc = Bt + (size_t)(n0 + rA) * K + lc * 8;
  bf16* Adst = As + tid * 8;
  bf16* Bdst = Bs + tid * 8;

  floatx4 acc[4][4] = {};
  const int quad = lane >> 4;
  const int lrow = lane & 15;
  const int xr   = lrow & 7;

  for (int k0 = 0; k0 < K; k0 += 64) {
#pragma unroll
    for (int j = 0; j < 4; j++) {
      gload16(Asrc + k0 + (size_t)j * 32 * K, Adst + j * 2048);
      gload16(Bsrc + k0 + (size_t)j * 32 * K, Bdst + j * 2048);
    }
    __syncthreads();

#pragma unroll
    for (int ks = 0; ks < 2; ks++) {
      bf16x8 af[4], bfr[4];
#pragma unroll
      for (int i = 0; i < 4; i++)
        af[i] = *(const bf16x8*)(As + (wm + i * 16 + lrow) * 64 + ((ks * 4 + quad) ^ xr) * 8);
#pragma unroll
      for (int j = 0; j < 4; j++)
        bfr[j] = *(const bf16x8*)(Bs + (wn + j * 16 + lrow) * 64 + ((ks * 4 + quad) ^ xr) * 8);
#pragma unroll
      for (int i = 0; i < 4; i++)
#pragma unroll
        for (int j = 0; j < 4; j++)
          acc[i][j] = __builtin_amdgcn_mfma_f32_16x16x32_bf16(af[i], bfr[j], acc[i][j], 0, 0, 0);
    }
    __syncthreads();
  }

#pragma unroll
  for (int i = 0; i < 4; i++) {
    const int gm_base = m0 + wm + i * 16 + quad * 4;
#pragma unroll
    for (int j = 0; j < 4; j++) {
      const int gn = n0 + wn + j * 16 + lrow;
      const float bv = (MODE != EP_QKV && bias) ? bias[gn] : 0.f;
#pragma unroll
      for (int r = 0; r < 4; r++) {
        const int gm = gm_base + r;
        float val = acc[i][j][r] + bv;
        if (MODE == EP_QKV) {
          if (gn < 768) ((bf16*)Cv)[(size_t)gm * 768 + gn] = (bf16)val;
          else          ((bf16*)Cv2)[(size_t)gm * 1536 + (gn - 768)] = (bf16)val;
        } else if (MODE == EP_FINAL) {
          // x dead after this GEMM: read-only x, route prefix rows to out.
          const size_t idx = (size_t)gm * ldc + gn;
          val += ((const float*)Cv)[idx];
          const int bloc = gm / 80;
          const int rr   = gm - bloc * 80;
          if (rr >= 40)
            ((float*)Cv2)[(size_t)bloc * 30720 + (size_t)(rr - 40) * 768 + gn] = val;
        } else {
          const size_t idx = (size_t)gm * ldc + gn;
          if (MODE == EP_STORE_BF16)      ((bf16*)Cv)[idx] = (bf16)val;
          else if (MODE == EP_STORE_F32)  ((float*)Cv)[idx] = val;
          else if (MODE == EP_ACCUM_F32)  ((float*)Cv)[idx] += val;
          else { val = val > 0.f ? val : 0.f; ((bf16*)Cv)[idx] = (bf16)val; }
        }
      }
    }
  }
}

// ---------------------------------------------------------------------------
// Transpose+cast (legacy path, small-ws fallbacks): in fp32 [K][N] row-major,
// cols [n_off + gx*64 ...) -> out bf16 [Npiece][K] row-major.
// ---------------------------------------------------------------------------
__global__ __launch_bounds__(256)
void transpose_cast(const float* __restrict__ in, bf16* __restrict__ out,
                    int K, int N, int n_off)
{
  __shared__ float t[64][65];
  const int n0 = blockIdx.x * 64, k0 = blockIdx.y * 64;
  const int c  = threadIdx.x & 63;
  const int r4 = threadIdx.x >> 6;
#pragma unroll
  for (int p = 0; p < 16; p++) {
    const int r = p * 4 + r4;
    t[r][c] = in[(size_t)(k0 + r) * N + n_off + n0 + c];
  }
  __syncthreads();
#pragma unroll
  for (int p = 0; p < 16; p++) {
    const int r = p * 4 + r4;
    out[(size_t)(n0 + r) * K + k0 + c] = (bf16)t[c][r];
  }
}

// ---------------------------------------------------------------------------
// prep_all: ONE launch replacing 43 serialized small launches.
// R4: transpose vectorized per G13 -- float4 global reads (16B/lane),
// uint2 bf16 global writes (8B/lane); LDS stride 65 fp32 keeps both phases
// at <=2-way bank aliasing (free). Was 4B-read/2B-write scalar at 35% HBM.
//   [0,9216)      weight transposes: l = bid/1152, r = bid%1152
//   [9216,9280)   lin_w  512x512
//   [9280,13120)  map_w  512x30720
//   [13120,20800) prefix_fill (7680 blocks)
//   [20800,20928) cast latent -> bf16 (128 blocks)
// ---------------------------------------------------------------------------
__global__ __launch_bounds__(256)
void prep_all(const float* __restrict__ wq, const float* __restrict__ wkv,
              const float* __restrict__ wo, const float* __restrict__ w1,
              const float* __restrict__ w2, const float* __restrict__ lin_w,
              const float* __restrict__ map_w, const float* __restrict__ latent,
              const float* __restrict__ prefix,
              bf16* __restrict__ wT, bf16* __restrict__ linT,
              bf16* __restrict__ mapT, bf16* __restrict__ latv,
              float* __restrict__ xw)
{
  __shared__ float t[64 * 65];
  const int bid = blockIdx.x;
  const int tid = threadIdx.x;

  if (bid < 13120) {
    const float* src; bf16* dst; int K, N, tile;
    if (bid < 9216) {
      const int l = bid / 1152;
      int r = bid - l * 1152;
      char* wl = (char*)wT + (size_t)l * 9437184;
      if (r < 144)      {            src = wq  + (size_t)l * 589824;  dst = (bf16*)wl;              K = 768;  N = 768;  }
      else if (r < 432) { r -= 144;  src = wkv + (size_t)l * 1179648; dst = (bf16*)(wl + 1179648);  K = 768;  N = 1536; }
      else if (r < 576) { r -= 432;  src = wo  + (size_t)l * 589824;  dst = (bf16*)(wl + 3538944);  K = 768;  N = 768;  }
      else if (r < 864) { r -= 576;  src = w1  + (size_t)l * 1179648; dst = (bf16*)(wl + 4718592);  K = 768;  N = 1536; }
      else              { r -= 864;  src = w2  + (size_t)l * 1179648; dst = (bf16*)(wl + 7077888);  K = 1536; N = 768;  }
      tile = r;
    } else if (bid < 9280) {
      tile = bid - 9216; src = lin_w; dst = linT; K = 512; N = 512;
    } else {
      tile = bid - 9280; src = map_w; dst = mapT; K = 512; N = 30720;
    }
    const int gxm = N >> 6;
    const int n0 = (tile % gxm) * 64, k0 = (tile / gxm) * 64;
    const int rr0 = tid >> 4;            // 0..15
    const int c4  = (tid & 15) * 4;      // col/k group of 4
#pragma unroll
    for (int p = 0; p < 4; p++) {
      const int r = p * 16 + rr0;
      const float4 v = *(const float4*)(src + (size_t)(k0 + r) * N + n0 + c4);
      float* tr = t + r * 65 + c4;
      tr[0] = v.x; tr[1] = v.y; tr[2] = v.z; tr[3] = v.w;
    }
    __syncthreads();
#pragma unroll
    for (int p = 0; p < 4; p++) {
      const int n = p * 16 + rr0;
      union { bf16 b[4]; uint2 u; } pk;
      pk.b[0] = (bf16)t[(c4 + 0) * 65 + n];
      pk.b[1] = (bf16)t[(c4 + 1) * 65 + n];
      pk.b[2] = (bf16)t[(c4 + 2) * 65 + n];
      pk.b[3] = (bf16)t[(c4 + 3) * 65 + n];
      *(uint2*)(dst + (size_t)(n0 + n) * K + k0 + c4) = pk.u;
    }
  } else if (bid < 20800) {
    const size_t i = (size_t)(bid - 13120) * 256 + tid;
    const size_t b = i / 7680, r = i - b * 7680;
    *(float4*)(xw + b * 61440 + 30720 + r * 4) = *(const float4*)(prefix + r * 4);
  } else {
    const size_t i = (size_t)(bid - 20800) * 256 + tid;
    const float4 v = *(const float4*)(latent + i * 4);
    union { bf16 b[4]; uint2 u; } pk;
    pk.b[0] = (bf16)v.x; pk.b[1] = (bf16)v.y; pk.b[2] = (bf16)v.z; pk.b[3] = (bf16)v.w;
    *(uint2*)(latv + i * 4) = pk.u;
  }
}

// ---------------------------------------------------------------------------
// LayerNorm: x fp32 (rows x 768) -> h bf16, one wave per row.
// ---------------------------------------------------------------------------
__global__ __launch_bounds__(256)
void ln_kernel(const float* __restrict__ x, const float* __restrict__ sc,
               const float* __restrict__ bi, bf16* __restrict__ h)
{
  const int wave = threadIdx.x >> 6, lane = threadIdx.x & 63;
  const size_t row = (size_t)blockIdx.x * 4 + wave;
  const float* xr = x + row * 768;
  float4 v[3];
  float sum = 0.f;
#pragma unroll
  for (int i = 0; i < 3; i++) {
    v[i] = *(const float4*)(xr + i * 256 + lane * 4);
    sum += v[i].x + v[i].y + v[i].z + v[i].w;
  }
#pragma unroll
  for (int off = 32; off > 0; off >>= 1) sum += __shfl_xor(sum, off, 64);
  const float mean = sum * (1.f / 768.f);
  float sq = 0.f;
#pragma unroll
  for (int i = 0; i < 3; i++) {
    const float a = v[i].x - mean, b = v[i].y - mean;
    const float c = v[i].z - mean, d = v[i].w - mean;
    sq += a * a + b * b + c * c + d * d;
  }
#pragma unroll
  for (int off = 32; off > 0; off >>= 1) sq += __shfl_xor(sq, off, 64);
  const float inv = rsqrtf(sq * (1.f / 768.f) + 1e-5f);
  bf16* hr = h + row * 768;
#pragma unroll
  for (int i = 0; i < 3; i++) {
    const int p = i * 256 + lane * 4;
    const float4 s4 = *(const float4*)(sc + p);
    const float4 b4 = *(const float4*)(bi + p);
    union { bf16 b[4]; uint2 u; } pk;
    pk.b[0] = (bf16)((v[i].x - mean) * inv * s4.x + b4.x);
    pk.b[1] = (bf16)((v[i].y - mean) * inv * s4.y + b4.y);
    pk.b[2] = (bf16)((v[i].z - mean) * inv * s4.z + b4.z);
    pk.b[3] = (bf16)((v[i].w - mean) * inv * s4.w + b4.w);
    *(uint2*)(hr + p) = pk.u;
  }
}

// ---------------------------------------------------------------------------
// MFMA attention: one block per (b, head). seq=80, DH=96.
// Row stride 104 elem (208B) -> 2 lanes/bank on ds_read_b128 (free).
// Wave-parallel softmax. R4: uint4 q/k staging (16B/lane), PV output staged
// in LDS (Kls, free after QK^T) then written as uint2 (8B/lane, 192B rows).
// ---------------------------------------------------------------------------
__global__ __launch_bounds__(256, 2)
void attn_kernel(const bf16* __restrict__ q, const bf16* __restrict__ kv,
                 bf16* __restrict__ o)
{
  __shared__ __align__(16) char smem[80128];
  bf16*  Qls = (bf16*)smem;            // 16640 B (aliased by P after softmax)
  bf16*  Kls = (bf16*)(smem + 16640);  // 16640 B (aliased by Ols after QK^T)
  bf16*  Vt  = (bf16*)(smem + 33280);  // 19968 B  [dh 96][seq 104 (80..95=0)]
  float* S   = (float*)(smem + 53248); // 26880 B  [80][84]
  bf16*  P   = Qls;                    // [80][104], k 80..95 zero-padded
  bf16*  Ols = Kls;                    // [80][104] output staging

  const int tid = threadIdx.x;
  const int wave = tid >> 6, lane = tid & 63;
  const int quad = lane >> 4, lrow = lane & 15;
  const int b = blockIdx.x >> 3, hh = blockIdx.x & 7;
  const bf16* qbp = q  + (size_t)b * 80 * 768  + hh * 96;
  const bf16* kbp = kv + (size_t)b * 80 * 1536 + hh * 96;
  const bf16* vbp = kbp + 768;
  bf16* obp = o + (size_t)b * 80 * 768 + hh * 96;

  // q, k: uint4 staging (rows of 96 bf16 = 12 x 16B)
  for (int i = tid; i < 960; i += 256) {
    const int n = i / 12, c = i - n * 12;
    const uint4 v = *(const uint4*)(qbp + (size_t)n * 768 + c * 8);
    *(uint4*)((uint*)Qls + n * 52 + c * 4) = v;
  }
  for (int i = tid; i < 960; i += 256) {
    const int n = i / 12, c = i - n * 12;
    const uint4 v = *(const uint4*)(kbp + (size_t)n * 1536 + c * 8);
    *(uint4*)((uint*)Kls + n * 52 + c * 4) = v;
  }
  // v: transpose staging (scalar; coalesced 192B global reads)
  for (int i = tid; i < 3840; i += 256) {
    const int n = i / 48, dp = i - n * 48;
    union { uint u; bf16 h[2]; } v;
    v.u = *(const uint*)(vbp + (size_t)n * 1536 + dp * 2);
    Vt[(2 * dp)     * 104 + n] = v.h[0];
    Vt[(2 * dp + 1) * 104 + n] = v.h[1];
  }
  for (int i = tid; i < 768; i += 256) {
    const int n = i >> 3, kp = i & 7;
    ((uint*)Vt)[n * 52 + 40 + kp] = 0u;
  }
  __syncthreads();

  const float scale = 0.1020620726159658f;  // 1/sqrt(96)
  for (int t = wave; t < 25; t += 4) {
    const int mi = t / 5, ni = t - (t / 5) * 5;
    floatx4 acc = {};
#pragma unroll
    for (int ks = 0; ks < 3; ks++) {
      const bf16x8 a  = *(const bf16x8*)(Qls + (mi * 16 + lrow) * 104 + ks * 32 + quad * 8);
      const bf16x8 bb = *(const bf16x8*)(Kls + (ni * 16 + lrow) * 104 + ks * 32 + quad * 8);
      acc = __builtin_amdgcn_mfma_f32_16x16x32_bf16(a, bb, acc, 0, 0, 0);
    }
#pragma unroll
    for (int r = 0; r < 4; r++)
      S[(mi * 16 + quad * 4 + r) * 84 + ni * 16 + lrow] = acc[r] * scale;
  }
  __syncthreads();

  // ---- wave-parallel softmax ----
  {
    const int row = tid >> 2;
    const int sl  = tid & 3;
    float* sr = S + row * 84;
    float mx = -1e30f;
#pragma unroll
    for (int j = 0; j < 20; j++) mx = fmaxf(mx, sr[sl + j * 4]);
    mx = fmaxf(mx, __shfl_xor(mx, 1, 64));
    mx = fmaxf(mx, __shfl_xor(mx, 2, 64));
    float e[20], sm = 0.f;
#pragma unroll
    for (int j = 0; j < 20; j++) { e[j] = __expf(sr[sl + j * 4] - mx); sm += e[j]; }
    sm += __shfl_xor(sm, 1, 64);
    sm += __shfl_xor(sm, 2, 64);
    const float inv = 1.f / sm;
#pragma unroll
    for (int j = 0; j < 20; j++) sr[sl + j * 4] = e[j] * inv;
    asm volatile("s_waitcnt lgkmcnt(0)" ::: "memory");
    uint* pr = (uint*)P + row * 52;
#pragma unroll
    for (int j = 0; j < 10; j++) {
      const int u = sl + j * 4;
      pr[u] = f2b2(sr[2 * u], sr[2 * u + 1]);
    }
    pr[40 + sl] = 0u;
    pr[44 + sl] = 0u;
  }
  {
    const int row = 64 + (tid >> 4);
    const int sl  = tid & 15;
    float* sr = S + row * 84;
    float mx = -1e30f;
#pragma unroll
    for (int j = 0; j < 5; j++) mx = fmaxf(mx, sr[sl + j * 16]);
    mx = fmaxf(mx, __shfl_xor(mx, 1, 64));
    mx = fmaxf(mx, __shfl_xor(mx, 2, 64));
    mx = fmaxf(mx, __shfl_xor(mx, 4, 64));
    mx = fmaxf(mx, __shfl_xor(mx, 8, 64));
    float e[5], sm = 0.f;
#pragma unroll
    for (int j = 0; j < 5; j++) { e[j] = __expf(sr[sl + j * 16] - mx); sm += e[j]; }
    sm += __shfl_xor(sm, 1, 64);
    sm += __shfl_xor(sm, 2, 64);
    sm += __shfl_xor(sm, 4, 64);
    sm += __shfl_xor(sm, 8, 64);
    const float inv = 1.f / sm;
#pragma unroll
    for (int j = 0; j < 5; j++) sr[sl + j * 16] = e[j] * inv;
    asm volatile("s_waitcnt lgkmcnt(0)" ::: "memory");
    uint* pr = (uint*)P + row * 52;
    for (int u = sl; u < 40; u += 16)
      pr[u] = f2b2(sr[2 * u], sr[2 * u + 1]);
    if (sl < 8) pr[40 + sl] = 0u;
  }
  __syncthreads();

  for (int t = wave; t < 30; t += 4) {
    const int mi = t / 6, ni = t - (t / 6) * 6;
    floatx4 acc = {};
#pragma unroll
    for (int ks = 0; ks < 3; ks++) {
      const bf16x8 a  = *(const bf16x8*)(P  + (mi * 16 + lrow) * 104 + ks * 32 + quad * 8);
      const bf16x8 bb = *(const bf16x8*)(Vt + (ni * 16 + lrow) * 104 + ks * 32 + quad * 8);
      acc = __builtin_amdgcn_mfma_f32_16x16x32_bf16(a, bb, acc, 0, 0, 0);
    }
#pragma unroll
    for (int r = 0; r < 4; r++)
      Ols[(mi * 16 + quad * 4 + r) * 104 + ni * 16 + lrow] = (bf16)acc[r];
  }
  __syncthreads();

  // vectorized output: 80 rows x 24 uint2 (192B contiguous per row)
  for (int i = tid; i < 1920; i += 256) {
    const int n = i / 24, c = i - n * 24;
    *(uint2*)((uint*)(obp + (size_t)n * 768) + c * 2) =
        *(const uint2*)((const uint*)(Ols + n * 104) + c * 2);
  }
}

// ---------------------------------------------------------------------------
// utility kernels (legacy small-ws paths)
// ---------------------------------------------------------------------------
__global__ __launch_bounds__(256)
void cast_f2b(const float* __restrict__ in, bf16* __restrict__ out, int n4)
{
  const int i = blockIdx.x * 256 + threadIdx.x;
  if (i >= n4) return;
  const float4 v = *(const float4*)(in + (size_t)i * 4);
  union { bf16 b[4]; uint2 u; } pk;
  pk.b[0] = (bf16)v.x; pk.b[1] = (bf16)v.y; pk.b[2] = (bf16)v.z; pk.b[3] = (bf16)v.w;
  *(uint2*)(out + (size_t)i * 4) = pk.u;
}

__global__ __launch_bounds__(256)
void prefix_fill(const float* __restrict__ pre, float* __restrict__ x)
{
  const size_t i = (size_t)blockIdx.x * 256 + threadIdx.x;
  const size_t b = i / 7680, r = i - b * 7680;
  *(float4*)(x + b * 61440 + 30720 + r * 4) = *(const float4*)(pre + r * 4);
}

__global__ __launch_bounds__(256)
void copy_out(const float* __restrict__ x, float* __restrict__ out)
{
  const size_t i = (size_t)blockIdx.x * 256 + threadIdx.x;
  const size_t b = i / 7680, r = i - b * 7680;
  *(float4*)(out + b * 30720 + r * 4) = *(const float4*)(x + b * 61440 + 30720 + r * 4);
}

// ---------------------------------------------------------------------------
extern "C" void kernel_launch(void* const* d_in, const int* in_sizes, int n_in,
                              void* d_out, int out_size, void* d_ws, size_t ws_size,
                              hipStream_t stream)
{
  (void)in_sizes; (void)n_in; (void)out_size;
  const float* latent = (const float*)d_in[0];
  const float* lin_w  = (const float*)d_in[1];
  const float* lin_b  = (const float*)d_in[2];
  const float* map_w  = (const float*)d_in[3];
  const float* map_b  = (const float*)d_in[4];
  const float* prefix = (const float*)d_in[5];
  const float* ln1_s  = (const float*)d_in[6];
  const float* ln1_b  = (const float*)d_in[7];
  const float* wq     = (const float*)d_in[8];
  const float* wkv    = (const float*)d_in[9];
  const float* wo     = (const float*)d_in[10];
  const float* bo     = (const float*)d_in[11];
  const float* ln2_s  = (const float*)d_in[12];
  const float* ln2_b  = (const float*)d_in[13];
  const float* w1     = (const float*)d_in[14];
  const float* b1     = (const float*)d_in[15];
  const float* w2     = (const float*)d_in[16];
  const float* b2     = (const float*)d_in[17];
  float* out = (float*)d_out;

  // --- workspace-size-adaptive config (ws_size constant -> graph-safe) ---
  int nchunk; bool wt_all;
  if      (ws_size >= 234000000ull) { nchunk = 1; wt_all = true;  }
  else if (ws_size >= 168000000ull) { nchunk = 1; wt_all = false; }
  else if (ws_size >= 121000000ull) { nchunk = 2; wt_all = false; }
  else if (ws_size >=  97000000ull) { nchunk = 4; wt_all = false; }
  else                              { nchunk = 8; wt_all = false; }
  const int Rc = 20480 / nchunk;         // rows per chunk
  const int Bc = 256 / nchunk;           // batches per chunk
  const int npiece = (nchunk <= 2) ? 1 : (nchunk == 4 ? 2 : 4);
  const int pieceN = 30720 / npiece;

  char* wsp = (char*)d_ws;
  auto alloc = [&](size_t bytes) -> char* {
    char* p = wsp; wsp += (bytes + 255) & ~(size_t)255; return p;
  };
  float* xw    = (float*)alloc(62914560ull);            // residual fp32, all rows
  char*  region = alloc((size_t)4608 * Rc);             // h + kv (chunk) | map stage
  char*  wT     = alloc(wt_all ? 75497472ull : 9437184ull);

  // map-stage aliases inside region
  bf16* mapT = (bf16*)region;
  char* tail = region + (size_t)pieceN * 512 * 2;
  bf16* latv = (bf16*)tail;
  bf16* latb = (bf16*)(tail + 262144);
  bf16* linT = (bf16*)(tail + 524288);
  // layer-loop aliases inside region
  bf16* hbuf = (bf16*)region;
  bf16* kvb  = (bf16*)(region + (size_t)Rc * 1536);
  bf16* qb   = (bf16*)d_out;   // dead until final write; holds q / attn-out

  const dim3 blk(256);

  // ---- prep + input projection
  if (wt_all) {
    prep_all<<<20928, blk, 0, stream>>>(wq, wkv, wo, w1, w2, lin_w, map_w,
                                        latent, prefix, (bf16*)wT, linT, mapT,
                                        latv, xw);
    gemm_bt<EP_STORE_BF16><<<dim3(4, 2), blk, 0, stream>>>(latv, linT, latb, nullptr, lin_b, 512, 512);
    gemm_bt<EP_STORE_F32><<<dim3(240, 2), blk, 0, stream>>>(
        latb, mapT, xw, nullptr, map_b, 512, 61440);
  } else {
    cast_f2b<<<128, blk, 0, stream>>>(latent, latv, 32768);
    transpose_cast<<<dim3(8, 8), blk, 0, stream>>>(lin_w, linT, 512, 512, 0);
    gemm_bt<EP_STORE_BF16><<<dim3(4, 2), blk, 0, stream>>>(latv, linT, latb, nullptr, lin_b, 512, 512);
    for (int p = 0; p < npiece; p++) {
      transpose_cast<<<dim3(pieceN / 64, 8), blk, 0, stream>>>(map_w, mapT, 512, 30720, p * pieceN);
      gemm_bt<EP_STORE_F32><<<dim3(pieceN / 128, 2), blk, 0, stream>>>(
          latb, mapT, xw + p * pieceN, nullptr, map_b + p * pieceN, 512, 61440);
    }
    prefix_fill<<<7680, blk, 0, stream>>>(prefix, xw);
  }

  // ---- transformer layers
  for (int l = 0; l < 8; l++) {
    char* wl = wT + (wt_all ? (size_t)l * 9437184 : 0);
    bf16* wqT  = (bf16*)wl;                    // wkvT contiguous after wqT
    bf16* woT  = (bf16*)(wl + 3538944);
    bf16* w1T  = (bf16*)(wl + 4718592);
    bf16* w2T  = (bf16*)(wl + 7077888);
    if (!wt_all) {
      transpose_cast<<<dim3(12, 12), blk, 0, stream>>>(wq + (size_t)l * 589824,  wqT,  768, 768, 0);
      transpose_cast<<<dim3(24, 12), blk, 0, stream>>>(wkv + (size_t)l * 1179648,(bf16*)(wl + 1179648), 768, 1536, 0);
      transpose_cast<<<dim3(12, 12), blk, 0, stream>>>(wo + (size_t)l * 589824,  woT,  768, 768, 0);
      transpose_cast<<<dim3(24, 12), blk, 0, stream>>>(w1 + (size_t)l * 1179648, w1T,  768, 1536, 0);
      transpose_cast<<<dim3(12, 24), blk, 0, stream>>>(w2 + (size_t)l * 1179648, w2T,  1536, 768, 0);
    }
    const bool fin = (l == 7) && (nchunk == 1);
    for (int c = 0; c < nchunk; c++) {
      float* xc = xw + (size_t)c * Rc * 768;
      ln_kernel<<<Rc / 4, blk, 0, stream>>>(xc, ln1_s + l * 768, ln1_b + l * 768, hbuf);
      gemm_bt<EP_QKV><<<dim3(18, Rc / 128), blk, 0, stream>>>(
          hbuf, wqT, qb, kvb, nullptr, 768, 0);
      attn_kernel<<<Bc * 8, blk, 0, stream>>>(qb, kvb, qb);
      gemm_bt<EP_ACCUM_F32><<<dim3(6, Rc / 128), blk, 0, stream>>>(
          qb, woT, xc, nullptr, bo + l * 768, 768, 768);
      ln_kernel<<<Rc / 4, blk, 0, stream>>>(xc, ln2_s + l * 768, ln2_b + l * 768, hbuf);
      gemm_bt<EP_RELU_BF16><<<dim3(12, Rc / 128), blk, 0, stream>>>(
          hbuf, w1T, kvb, nullptr, b1 + l * 1536, 768, 1536);
      if (fin) {
        gemm_bt<EP_FINAL><<<dim3(6, Rc / 128), blk, 0, stream>>>(
            kvb, w2T, xc, out, b2 + l * 768, 1536, 768);
      } else {
        gemm_bt<EP_ACCUM_F32><<<dim3(6, Rc / 128), blk, 0, stream>>>(
            kvb, w2T, xc, nullptr, b2 + l * 768, 1536, 768);
      }
    }
  }
  if (!(nchunk == 1))
    copy_out<<<7680, blk, 0, stream>>>(xw, out);
}

// Round 6
// 2858.725 us; speedup vs baseline: 1.0639x; 1.0639x over previous
//
#include <hip/hip_runtime.h>
#include <hip/hip_bf16.h>
#include <stdint.h>

typedef __bf16 bf16;
typedef unsigned int uint;
typedef __attribute__((ext_vector_type(8))) __bf16 bf16x8;
typedef __attribute__((ext_vector_type(4))) float floatx4;

#define DEV static __device__ __forceinline__

typedef const __attribute__((address_space(1))) void* gptr_t;
typedef __attribute__((address_space(3))) void* lptr_t;

DEV void gload16(const void* g, void* l) {
  __builtin_amdgcn_global_load_lds((gptr_t)g, (lptr_t)l, 16, 0, 0);
}

DEV uint f2b2(float x, float y) {
  union { bf16 h[2]; uint u; } pk;
  pk.h[0] = (bf16)x; pk.h[1] = (bf16)y;
  return pk.u;
}

// ---------------------------------------------------------------------------
// GEMM: C[M][N] (op)= A[M][K] * Bt[N][K]^T (+ bias[n])
// 128x128 tile, BK=64, 256 threads, MFMA 16x16x32 bf16. XOR-8 swizzled LDS,
// XCD-aware block swizzle. Proven ~875 TF @ K=768 (structural ceiling for
// this K per R1 experiment: 256^2 8-phase regressed at NT=12).
// ---------------------------------------------------------------------------
#define EP_STORE_BF16 0
#define EP_STORE_F32  1
#define EP_ACCUM_F32  2
#define EP_RELU_BF16  3
#define EP_QKV        4
#define EP_FINAL      5   // read C(fp32), add; write prefix rows to out fp32

template<int MODE>
__global__ __launch_bounds__(256, 4)
void gemm_bt(const bf16* __restrict__ A, const bf16* __restrict__ Bt,
             void* __restrict__ Cv, void* __restrict__ Cv2,
             const float* __restrict__ bias, int K, int ldc)
{
  __shared__ bf16 As[128 * 64];
  __shared__ bf16 Bs[128 * 64];
  const int tid  = threadIdx.x;
  const int wave = tid >> 6;
  const int lane = tid & 63;

  // XCD-aware swizzle (identity when gridDim.y % 8 != 0)
  int bx = blockIdx.x, by = blockIdx.y;
  const int gx = (int)gridDim.x, gy = (int)gridDim.y;
  if ((gy & 7) == 0) {
    const int flat = by * gx + bx;
    const int xcd  = flat & 7;
    const int s    = flat >> 3;
    const int rows_per = gy >> 3;
    const int m_local  = s / gx;
    bx = s - m_local * gx;
    by = xcd * rows_per + m_local;
  }
  const int m0 = by * 128;
  const int n0 = bx * 128;
  const int wm = (wave >> 1) * 64;
  const int wn = (wave & 1) * 64;

  const int rA = tid >> 3;                 // local row 0..31 (call adds j*32)
  const int lc = (tid & 7) ^ (rA & 7);     // logical 16B-chunk (const: 32%8==0)
  const bf16* Asrc = A  + (size_t)(m0 + rA) * K + lc * 8;
  const bf16* Bsrc = Bt + (size_t)(n0 + rA) * K + lc * 8;
  bf16* Adst = As + tid * 8;
  bf16* Bdst = Bs + tid * 8;

  floatx4 acc[4][4] = {};
  const int quad = lane >> 4;
  const int lrow = lane & 15;
  const int xr   = lrow & 7;

  for (int k0 = 0; k0 < K; k0 += 64) {
#pragma unroll
    for (int j = 0; j < 4; j++) {
      gload16(Asrc + k0 + (size_t)j * 32 * K, Adst + j * 2048);
      gload16(Bsrc + k0 + (size_t)j * 32 * K, Bdst + j * 2048);
    }
    __syncthreads();

#pragma unroll
    for (int ks = 0; ks < 2; ks++) {
      bf16x8 af[4], bfr[4];
#pragma unroll
      for (int i = 0; i < 4; i++)
        af[i] = *(const bf16x8*)(As + (wm + i * 16 + lrow) * 64 + ((ks * 4 + quad) ^ xr) * 8);
#pragma unroll
      for (int j = 0; j < 4; j++)
        bfr[j] = *(const bf16x8*)(Bs + (wn + j * 16 + lrow) * 64 + ((ks * 4 + quad) ^ xr) * 8);
#pragma unroll
      for (int i = 0; i < 4; i++)
#pragma unroll
        for (int j = 0; j < 4; j++)
          acc[i][j] = __builtin_amdgcn_mfma_f32_16x16x32_bf16(af[i], bfr[j], acc[i][j], 0, 0, 0);
    }
    __syncthreads();
  }

#pragma unroll
  for (int i = 0; i < 4; i++) {
    const int gm_base = m0 + wm + i * 16 + quad * 4;
#pragma unroll
    for (int j = 0; j < 4; j++) {
      const int gn = n0 + wn + j * 16 + lrow;
      const float bv = (MODE != EP_QKV && bias) ? bias[gn] : 0.f;
#pragma unroll
      for (int r = 0; r < 4; r++) {
        const int gm = gm_base + r;
        float val = acc[i][j][r] + bv;
        if (MODE == EP_QKV) {
          if (gn < 768) ((bf16*)Cv)[(size_t)gm * 768 + gn] = (bf16)val;
          else          ((bf16*)Cv2)[(size_t)gm * 1536 + (gn - 768)] = (bf16)val;
        } else if (MODE == EP_FINAL) {
          // x dead after this GEMM: read-only x, route prefix rows to out.
          const size_t idx = (size_t)gm * ldc + gn;
          val += ((const float*)Cv)[idx];
          const int bloc = gm / 80;
          const int rr   = gm - bloc * 80;
          if (rr >= 40)
            ((float*)Cv2)[(size_t)bloc * 30720 + (size_t)(rr - 40) * 768 + gn] = val;
        } else {
          const size_t idx = (size_t)gm * ldc + gn;
          if (MODE == EP_STORE_BF16)      ((bf16*)Cv)[idx] = (bf16)val;
          else if (MODE == EP_STORE_F32)  ((float*)Cv)[idx] = val;
          else if (MODE == EP_ACCUM_F32)  ((float*)Cv)[idx] += val;
          else { val = val > 0.f ? val : 0.f; ((bf16*)Cv)[idx] = (bf16)val; }
        }
      }
    }
  }
}

// ---------------------------------------------------------------------------
// Transpose+cast (legacy path, small-ws fallbacks): in fp32 [K][N] row-major,
// cols [n_off + gx*64 ...) -> out bf16 [Npiece][K] row-major.
// ---------------------------------------------------------------------------
__global__ __launch_bounds__(256)
void transpose_cast(const float* __restrict__ in, bf16* __restrict__ out,
                    int K, int N, int n_off)
{
  __shared__ float t[64][65];
  const int n0 = blockIdx.x * 64, k0 = blockIdx.y * 64;
  const int c  = threadIdx.x & 63;
  const int r4 = threadIdx.x >> 6;
#pragma unroll
  for (int p = 0; p < 16; p++) {
    const int r = p * 4 + r4;
    t[r][c] = in[(size_t)(k0 + r) * N + n_off + n0 + c];
  }
  __syncthreads();
#pragma unroll
  for (int p = 0; p < 16; p++) {
    const int r = p * 4 + r4;
    out[(size_t)(n0 + r) * K + k0 + c] = (bf16)t[c][r];
  }
}

// ---------------------------------------------------------------------------
// prep_all: ONE launch replacing 43 serialized small launches.
// R5/R6: transpose retiled to 128k x 64n -- global reads 256B/row segments,
// global WRITES 256B contiguous per output row (was 128B @ 1.5KB stride).
// LDS [128][65] fp32 (33.3KB, 4 blocks/CU). Read-phase LDS writes 2-way
// (free); write-phase LDS reads 4-way (1.58x, minor phase).
//   [0,4608)      weight transposes: l = bid/576, r = bid%576
//   [4608,4640)   lin_w  512x512   (32 tiles)
//   [4640,6560)   map_w  512x30720 (1920 tiles)
//   [6560,14240)  prefix_fill (7680 blocks)
//   [14240,14368) cast latent -> bf16 (128 blocks)
// ---------------------------------------------------------------------------
__global__ __launch_bounds__(256)
void prep_all(const float* __restrict__ wq, const float* __restrict__ wkv,
              const float* __restrict__ wo, const float* __restrict__ w1,
              const float* __restrict__ w2, const float* __restrict__ lin_w,
              const float* __restrict__ map_w, const float* __restrict__ latent,
              const float* __restrict__ prefix,
              bf16* __restrict__ wT, bf16* __restrict__ linT,
              bf16* __restrict__ mapT, bf16* __restrict__ latv,
              float* __restrict__ xw)
{
  __shared__ float t[128 * 65];
  const int bid = blockIdx.x;
  const int tid = threadIdx.x;

  if (bid < 6560) {
    const float* src; bf16* dst; int K, N, tile;
    if (bid < 4608) {
      const int l = bid / 576;
      int r = bid - l * 576;
      char* wl = (char*)wT + (size_t)l * 9437184;
      if (r < 72)       {            src = wq  + (size_t)l * 589824;  dst = (bf16*)wl;              K = 768;  N = 768;  }
      else if (r < 216) { r -= 72;   src = wkv + (size_t)l * 1179648; dst = (bf16*)(wl + 1179648);  K = 768;  N = 1536; }
      else if (r < 288) { r -= 216;  src = wo  + (size_t)l * 589824;  dst = (bf16*)(wl + 3538944);  K = 768;  N = 768;  }
      else if (r < 432) { r -= 288;  src = w1  + (size_t)l * 1179648; dst = (bf16*)(wl + 4718592);  K = 768;  N = 1536; }
      else              { r -= 432;  src = w2  + (size_t)l * 1179648; dst = (bf16*)(wl + 7077888);  K = 1536; N = 768;  }
      tile = r;
    } else if (bid < 4640) {
      tile = bid - 4608; src = lin_w; dst = linT; K = 512; N = 512;
    } else {
      tile = bid - 4640; src = map_w; dst = mapT; K = 512; N = 30720;
    }
    const int gxm = N >> 6;                  // tiles along n
    const int n0 = (tile % gxm) * 64;
    const int k0 = (tile / gxm) * 128;
    // ---- read: 8 passes x 16 k-rows; lane covers 16B of a 256B row-segment
    const int kr = tid >> 4;                 // 0..15
    const int c4 = (tid & 15) * 4;
#pragma unroll
    for (int p = 0; p < 8; p++) {
      const int k = p * 16 + kr;
      const float4 v = *(const float4*)(src + (size_t)(k0 + k) * N + n0 + c4);
      float* tr = t + k * 65 + c4;
      tr[0] = v.x; tr[1] = v.y; tr[2] = v.z; tr[3] = v.w;
    }
    __syncthreads();
    // ---- write: 8 passes x 8 n-rows; 32 lanes cover 256B contiguous per row
    const int nr = tid >> 5;                 // 0..7
    const int k4 = (tid & 31) * 4;
#pragma unroll
    for (int p = 0; p < 8; p++) {
      const int n = p * 8 + nr;
      union { bf16 b[4]; uint2 u; } pk;
      pk.b[0] = (bf16)t[(k4 + 0) * 65 + n];
      pk.b[1] = (bf16)t[(k4 + 1) * 65 + n];
      pk.b[2] = (bf16)t[(k4 + 2) * 65 + n];
      pk.b[3] = (bf16)t[(k4 + 3) * 65 + n];
      *(uint2*)(dst + (size_t)(n0 + n) * K + k0 + k4) = pk.u;
    }
  } else if (bid < 14240) {
    const size_t i = (size_t)(bid - 6560) * 256 + tid;
    const size_t b = i / 7680, r = i - b * 7680;
    *(float4*)(xw + b * 61440 + 30720 + r * 4) = *(const float4*)(prefix + r * 4);
  } else {
    const size_t i = (size_t)(bid - 14240) * 256 + tid;
    const float4 v = *(const float4*)(latent + i * 4);
    union { bf16 b[4]; uint2 u; } pk;
    pk.b[0] = (bf16)v.x; pk.b[1] = (bf16)v.y; pk.b[2] = (bf16)v.z; pk.b[3] = (bf16)v.w;
    *(uint2*)(latv + i * 4) = pk.u;
  }
}

// ---------------------------------------------------------------------------
// LayerNorm: x fp32 (rows x 768) -> h bf16, one wave per row.
// ---------------------------------------------------------------------------
__global__ __launch_bounds__(256)
void ln_kernel(const float* __restrict__ x, const float* __restrict__ sc,
               const float* __restrict__ bi, bf16* __restrict__ h)
{
  const int wave = threadIdx.x >> 6, lane = threadIdx.x & 63;
  const size_t row = (size_t)blockIdx.x * 4 + wave;
  const float* xr = x + row * 768;
  float4 v[3];
  float sum = 0.f;
#pragma unroll
  for (int i = 0; i < 3; i++) {
    v[i] = *(const float4*)(xr + i * 256 + lane * 4);
    sum += v[i].x + v[i].y + v[i].z + v[i].w;
  }
#pragma unroll
  for (int off = 32; off > 0; off >>= 1) sum += __shfl_xor(sum, off, 64);
  const float mean = sum * (1.f / 768.f);
  float sq = 0.f;
#pragma unroll
  for (int i = 0; i < 3; i++) {
    const float a = v[i].x - mean, b = v[i].y - mean;
    const float c = v[i].z - mean, d = v[i].w - mean;
    sq += a * a + b * b + c * c + d * d;
  }
#pragma unroll
  for (int off = 32; off > 0; off >>= 1) sq += __shfl_xor(sq, off, 64);
  const float inv = rsqrtf(sq * (1.f / 768.f) + 1e-5f);
  bf16* hr = h + row * 768;
#pragma unroll
  for (int i = 0; i < 3; i++) {
    const int p = i * 256 + lane * 4;
    const float4 s4 = *(const float4*)(sc + p);
    const float4 b4 = *(const float4*)(bi + p);
    union { bf16 b[4]; uint2 u; } pk;
    pk.b[0] = (bf16)((v[i].x - mean) * inv * s4.x + b4.x);
    pk.b[1] = (bf16)((v[i].y - mean) * inv * s4.y + b4.y);
    pk.b[2] = (bf16)((v[i].z - mean) * inv * s4.z + b4.z);
    pk.b[3] = (bf16)((v[i].w - mean) * inv * s4.w + b4.w);
    *(uint2*)(hr + p) = pk.u;
  }
}

// ---------------------------------------------------------------------------
// MFMA attention: one block per (b, head). seq=80, DH=96.  (R3-proven.)
// Row stride 104 elem (208B) -> 2 lanes/bank on ds_read_b128 (free).
// Wave-parallel softmax (all 256 threads active).
// ---------------------------------------------------------------------------
__global__ __launch_bounds__(256, 2)
void attn_kernel(const bf16* __restrict__ q, const bf16* __restrict__ kv,
                 bf16* __restrict__ o)
{
  __shared__ __align__(16) char smem[80128];
  bf16*  Qls = (bf16*)smem;            // 16640 B (aliased by P after softmax)
  bf16*  Kls = (bf16*)(smem + 16640);  // 16640 B
  bf16*  Vt  = (bf16*)(smem + 33280);  // 19968 B  [dh 96][seq 104 (80..95=0)]
  float* S   = (float*)(smem + 53248); // 26880 B  [80][84]
  bf16*  P   = Qls;                    // [80][104], k 80..95 zero-padded

  const int tid = threadIdx.x;
  const int wave = tid >> 6, lane = tid & 63;
  const int quad = lane >> 4, lrow = lane & 15;
  const int b = blockIdx.x >> 3, hh = blockIdx.x & 7;
  const bf16* qbp = q  + (size_t)b * 80 * 768  + hh * 96;
  const bf16* kbp = kv + (size_t)b * 80 * 1536 + hh * 96;
  const bf16* vbp = kbp + 768;
  bf16* obp = o + (size_t)b * 80 * 768 + hh * 96;

  for (int i = tid; i < 3840; i += 256) {
    const int n = i / 48, dp = i - n * 48;
    ((uint*)Qls)[n * 52 + dp] = *(const uint*)(qbp + (size_t)n * 768  + dp * 2);
    ((uint*)Kls)[n * 52 + dp] = *(const uint*)(kbp + (size_t)n * 1536 + dp * 2);
    union { uint u; bf16 h[2]; } v;
    v.u = *(const uint*)(vbp + (size_t)n * 1536 + dp * 2);
    Vt[(2 * dp)     * 104 + n] = v.h[0];
    Vt[(2 * dp + 1) * 104 + n] = v.h[1];
  }
  for (int i = tid; i < 768; i += 256) {
    const int n = i >> 3, kp = i & 7;
    ((uint*)Vt)[n * 52 + 40 + kp] = 0u;
  }
  __syncthreads();

  const float scale = 0.1020620726159658f;  // 1/sqrt(96)
  for (int t = wave; t < 25; t += 4) {
    const int mi = t / 5, ni = t - (t / 5) * 5;
    floatx4 acc = {};
#pragma unroll
    for (int ks = 0; ks < 3; ks++) {
      const bf16x8 a  = *(const bf16x8*)(Qls + (mi * 16 + lrow) * 104 + ks * 32 + quad * 8);
      const bf16x8 bb = *(const bf16x8*)(Kls + (ni * 16 + lrow) * 104 + ks * 32 + quad * 8);
      acc = __builtin_amdgcn_mfma_f32_16x16x32_bf16(a, bb, acc, 0, 0, 0);
    }
#pragma unroll
    for (int r = 0; r < 4; r++)
      S[(mi * 16 + quad * 4 + r) * 84 + ni * 16 + lrow] = acc[r] * scale;
  }
  __syncthreads();

  // ---- wave-parallel softmax ----
  {
    const int row = tid >> 2;
    const int sl  = tid & 3;
    float* sr = S + row * 84;
    float mx = -1e30f;
#pragma unroll
    for (int j = 0; j < 20; j++) mx = fmaxf(mx, sr[sl + j * 4]);
    mx = fmaxf(mx, __shfl_xor(mx, 1, 64));
    mx = fmaxf(mx, __shfl_xor(mx, 2, 64));
    float e[20], sm = 0.f;
#pragma unroll
    for (int j = 0; j < 20; j++) { e[j] = __expf(sr[sl + j * 4] - mx); sm += e[j]; }
    sm += __shfl_xor(sm, 1, 64);
    sm += __shfl_xor(sm, 2, 64);
    const float inv = 1.f / sm;
#pragma unroll
    for (int j = 0; j < 20; j++) sr[sl + j * 4] = e[j] * inv;
    asm volatile("s_waitcnt lgkmcnt(0)" ::: "memory");
    uint* pr = (uint*)P + row * 52;
#pragma unroll
    for (int j = 0; j < 10; j++) {
      const int u = sl + j * 4;
      pr[u] = f2b2(sr[2 * u], sr[2 * u + 1]);
    }
    pr[40 + sl] = 0u;
    pr[44 + sl] = 0u;
  }
  {
    const int row = 64 + (tid >> 4);
    const int sl  = tid & 15;
    float* sr = S + row * 84;
    float mx = -1e30f;
#pragma unroll
    for (int j = 0; j < 5; j++) mx = fmaxf(mx, sr[sl + j * 16]);
    mx = fmaxf(mx, __shfl_xor(mx, 1, 64));
    mx = fmaxf(mx, __shfl_xor(mx, 2, 64));
    mx = fmaxf(mx, __shfl_xor(mx, 4, 64));
    mx = fmaxf(mx, __shfl_xor(mx, 8, 64));
    float e[5], sm = 0.f;
#pragma unroll
    for (int j = 0; j < 5; j++) { e[j] = __expf(sr[sl + j * 16] - mx); sm += e[j]; }
    sm += __shfl_xor(sm, 1, 64);
    sm += __shfl_xor(sm, 2, 64);
    sm += __shfl_xor(sm, 4, 64);
    sm += __shfl_xor(sm, 8, 64);
    const float inv = 1.f / sm;
#pragma unroll
    for (int j = 0; j < 5; j++) sr[sl + j * 16] = e[j] * inv;
    asm volatile("s_waitcnt lgkmcnt(0)" ::: "memory");
    uint* pr = (uint*)P + row * 52;
    for (int u = sl; u < 40; u += 16)
      pr[u] = f2b2(sr[2 * u], sr[2 * u + 1]);
    if (sl < 8) pr[40 + sl] = 0u;
  }
  __syncthreads();

  for (int t = wave; t < 30; t += 4) {
    const int mi = t / 6, ni = t - (t / 6) * 6;
    floatx4 acc = {};
#pragma unroll
    for (int ks = 0; ks < 3; ks++) {
      const bf16x8 a  = *(const bf16x8*)(P  + (mi * 16 + lrow) * 104 + ks * 32 + quad * 8);
      const bf16x8 bb = *(const bf16x8*)(Vt + (ni * 16 + lrow) * 104 + ks * 32 + quad * 8);
      acc = __builtin_amdgcn_mfma_f32_16x16x32_bf16(a, bb, acc, 0, 0, 0);
    }
#pragma unroll
    for (int r = 0; r < 4; r++)
      obp[(size_t)(mi * 16 + quad * 4 + r) * 768 + ni * 16 + lrow] = (bf16)acc[r];
  }
}

// ---------------------------------------------------------------------------
// utility kernels (legacy small-ws paths)
// ---------------------------------------------------------------------------
__global__ __launch_bounds__(256)
void cast_f2b(const float* __restrict__ in, bf16* __restrict__ out, int n4)
{
  const int i = blockIdx.x * 256 + threadIdx.x;
  if (i >= n4) return;
  const float4 v = *(const float4*)(in + (size_t)i * 4);
  union { bf16 b[4]; uint2 u; } pk;
  pk.b[0] = (bf16)v.x; pk.b[1] = (bf16)v.y; pk.b[2] = (bf16)v.z; pk.b[3] = (bf16)v.w;
  *(uint2*)(out + (size_t)i * 4) = pk.u;
}

__global__ __launch_bounds__(256)
void prefix_fill(const float* __restrict__ pre, float* __restrict__ x)
{
  const size_t i = (size_t)blockIdx.x * 256 + threadIdx.x;
  const size_t b = i / 7680, r = i - b * 7680;
  *(float4*)(x + b * 61440 + 30720 + r * 4) = *(const float4*)(pre + r * 4);
}

__global__ __launch_bounds__(256)
void copy_out(const float* __restrict__ x, float* __restrict__ out)
{
  const size_t i = (size_t)blockIdx.x * 256 + threadIdx.x;
  const size_t b = i / 7680, r = i - b * 7680;
  *(float4*)(out + b * 30720 + r * 4) = *(const float4*)(x + b * 61440 + 30720 + r * 4);
}

// ---------------------------------------------------------------------------
extern "C" void kernel_launch(void* const* d_in, const int* in_sizes, int n_in,
                              void* d_out, int out_size, void* d_ws, size_t ws_size,
                              hipStream_t stream)
{
  (void)in_sizes; (void)n_in; (void)out_size;
  const float* latent = (const float*)d_in[0];
  const float* lin_w  = (const float*)d_in[1];
  const float* lin_b  = (const float*)d_in[2];
  const float* map_w  = (const float*)d_in[3];
  const float* map_b  = (const float*)d_in[4];
  const float* prefix = (const float*)d_in[5];
  const float* ln1_s  = (const float*)d_in[6];
  const float* ln1_b  = (const float*)d_in[7];
  const float* wq     = (const float*)d_in[8];
  const float* wkv    = (const float*)d_in[9];
  const float* wo     = (const float*)d_in[10];
  const float* bo     = (const float*)d_in[11];
  const float* ln2_s  = (const float*)d_in[12];
  const float* ln2_b  = (const float*)d_in[13];
  const float* w1     = (const float*)d_in[14];
  const float* b1     = (const float*)d_in[15];
  const float* w2     = (const float*)d_in[16];
  const float* b2     = (const float*)d_in[17];
  float* out = (float*)d_out;

  // --- workspace-size-adaptive config (ws_size constant -> graph-safe) ---
  int nchunk; bool wt_all;
  if      (ws_size >= 234000000ull) { nchunk = 1; wt_all = true;  }
  else if (ws_size >= 168000000ull) { nchunk = 1; wt_all = false; }
  else if (ws_size >= 121000000ull) { nchunk = 2; wt_all = false; }
  else if (ws_size >=  97000000ull) { nchunk = 4; wt_all = false; }
  else                              { nchunk = 8; wt_all = false; }
  const int Rc = 20480 / nchunk;         // rows per chunk
  const int Bc = 256 / nchunk;           // batches per chunk
  const int npiece = (nchunk <= 2) ? 1 : (nchunk == 4 ? 2 : 4);
  const int pieceN = 30720 / npiece;

  char* wsp = (char*)d_ws;
  auto alloc = [&](size_t bytes) -> char* {
    char* p = wsp; wsp += (bytes + 255) & ~(size_t)255; return p;
  };
  float* xw    = (float*)alloc(62914560ull);            // residual fp32, all rows
  char*  region = alloc((size_t)4608 * Rc);             // h + kv (chunk) | map stage
  char*  wT     = alloc(wt_all ? 75497472ull : 9437184ull);

  // map-stage aliases inside region
  bf16* mapT = (bf16*)region;
  char* tail = region + (size_t)pieceN * 512 * 2;
  bf16* latv = (bf16*)tail;
  bf16* latb = (bf16*)(tail + 262144);
  bf16* linT = (bf16*)(tail + 524288);
  // layer-loop aliases inside region
  bf16* hbuf = (bf16*)region;
  bf16* kvb  = (bf16*)(region + (size_t)Rc * 1536);
  bf16* qb   = (bf16*)d_out;   // dead until final write; holds q / attn-out

  const dim3 blk(256);

  // ---- prep + input projection
  if (wt_all) {
    prep_all<<<14368, blk, 0, stream>>>(wq, wkv, wo, w1, w2, lin_w, map_w,
                                        latent, prefix, (bf16*)wT, linT, mapT,
                                        latv, xw);
    gemm_bt<EP_STORE_BF16><<<dim3(4, 2), blk, 0, stream>>>(latv, linT, latb, nullptr, lin_b, 512, 512);
    gemm_bt<EP_STORE_F32><<<dim3(240, 2), blk, 0, stream>>>(
        latb, mapT, xw, nullptr, map_b, 512, 61440);
  } else {
    cast_f2b<<<128, blk, 0, stream>>>(latent, latv, 32768);
    transpose_cast<<<dim3(8, 8), blk, 0, stream>>>(lin_w, linT, 512, 512, 0);
    gemm_bt<EP_STORE_BF16><<<dim3(4, 2), blk, 0, stream>>>(latv, linT, latb, nullptr, lin_b, 512, 512);
    for (int p = 0; p < npiece; p++) {
      transpose_cast<<<dim3(pieceN / 64, 8), blk, 0, stream>>>(map_w, mapT, 512, 30720, p * pieceN);
      gemm_bt<EP_STORE_F32><<<dim3(pieceN / 128, 2), blk, 0, stream>>>(
          latb, mapT, xw + p * pieceN, nullptr, map_b + p * pieceN, 512, 61440);
    }
    prefix_fill<<<7680, blk, 0, stream>>>(prefix, xw);
  }

  // ---- transformer layers
  for (int l = 0; l < 8; l++) {
    char* wl = wT + (wt_all ? (size_t)l * 9437184 : 0);
    bf16* wqT  = (bf16*)wl;                    // wkvT contiguous after wqT
    bf16* woT  = (bf16*)(wl + 3538944);
    bf16* w1T  = (bf16*)(wl + 4718592);
    bf16* w2T  = (bf16*)(wl + 7077888);
    if (!wt_all) {
      transpose_cast<<<dim3(12, 12), blk, 0, stream>>>(wq + (size_t)l * 589824,  wqT,  768, 768, 0);
      transpose_cast<<<dim3(24, 12), blk, 0, stream>>>(wkv + (size_t)l * 1179648,(bf16*)(wl + 1179648), 768, 1536, 0);
      transpose_cast<<<dim3(12, 12), blk, 0, stream>>>(wo + (size_t)l * 589824,  woT,  768, 768, 0);
      transpose_cast<<<dim3(24, 12), blk, 0, stream>>>(w1 + (size_t)l * 1179648, w1T,  768, 1536, 0);
      transpose_cast<<<dim3(12, 24), blk, 0, stream>>>(w2 + (size_t)l * 1179648, w2T,  1536, 768, 0);
    }
    const bool fin = (l == 7) && (nchunk == 1);
    for (int c = 0; c < nchunk; c++) {
      float* xc = xw + (size_t)c * Rc * 768;
      ln_kernel<<<Rc / 4, blk, 0, stream>>>(xc, ln1_s + l * 768, ln1_b + l * 768, hbuf);
      gemm_bt<EP_QKV><<<dim3(18, Rc / 128), blk, 0, stream>>>(
          hbuf, wqT, qb, kvb, nullptr, 768, 0);
      attn_kernel<<<Bc * 8, blk, 0, stream>>>(qb, kvb, qb);
      gemm_bt<EP_ACCUM_F32><<<dim3(6, Rc / 128), blk, 0, stream>>>(
          qb, woT, xc, nullptr, bo + l * 768, 768, 768);
      ln_kernel<<<Rc / 4, blk, 0, stream>>>(xc, ln2_s + l * 768, ln2_b + l * 768, hbuf);
      gemm_bt<EP_RELU_BF16><<<dim3(12, Rc / 128), blk, 0, stream>>>(
          hbuf, w1T, kvb, nullptr, b1 + l * 1536, 768, 1536);
      if (fin) {
        gemm_bt<EP_FINAL><<<dim3(6, Rc / 128), blk, 0, stream>>>(
            kvb, w2T, xc, out, b2 + l * 768, 1536, 768);
      } else {
        gemm_bt<EP_ACCUM_F32><<<dim3(6, Rc / 128), blk, 0, stream>>>(
            kvb, w2T, xc, nullptr, b2 + l * 768, 1536, 768);
      }
    }
  }
  if (!(nchunk == 1))
    copy_out<<<7680, blk, 0, stream>>>(xw, out);
}